// Round 7
// baseline (220.936 us; speedup 1.0000x reference)
//
#include <hip/hip_runtime.h>

#define NB 8      // batches
#define NT 16     // timesteps
#define NN 256    // points
#define NS 3      // scales

typedef float f32x4 __attribute__((ext_vector_type(4)));
typedef int   i32x4 __attribute__((ext_vector_type(4)));

// ---------------------------------------------------------------------------
// Kernel 1: leader-clustering groups, ONE WAVE per batch, zero barriers.
// Bit-exact distance math (no fma contraction, correctly-rounded sqrt):
// group ids have zero error tolerance.
// ---------------------------------------------------------------------------
__global__ __launch_bounds__(64) void groups_kernel(
    const float* __restrict__ positions,
    float* __restrict__ out_groups_f,
    int* __restrict__ out_groups_i)
{
    const int b    = blockIdx.x;
    const int lane = threadIdx.x;

    const float2* __restrict__ P =
        ((const float2*)positions) + ((size_t)b * NT + (NT - 1)) * NN;

    float px[4], py[4];
#pragma unroll
    for (int k = 0; k < 4; ++k) {
        const float2 p = P[k * 64 + lane];
        px[k] = p.x; py[k] = p.y;
    }

    unsigned long long amask[4] = {0ull, 0ull, 0ull, 0ull};
    int grp[4] = {0, 0, 0, 0};
    int cur = 0;

#pragma unroll
    for (int ki = 0; ki < 4; ++ki) {
        for (int li = 0; li < 64; ++li) {
            if ((amask[ki] >> li) & 1ull) continue;
            const float pix = __shfl(px[ki], li);
            const float piy = __shfl(py[ki], li);
#pragma unroll
            for (int k = ki; k < 4; ++k) {
                const bool elig = (k > ki) || (lane >= li);
                const bool unas = (((amask[k] >> lane) & 1ull) == 0ull);
                const float dx = pix - px[k];
                const float dy = piy - py[k];
                const float sq = __fadd_rn(__fmul_rn(dx, dx), __fmul_rn(dy, dy));
                const float d  = (sq > 0.0f) ? __fsqrt_rn(sq) : 0.0f;
                const bool newly = elig && unas && (d <= 2.0f);
                const unsigned long long nb = __ballot(newly);
                amask[k] |= nb;
                if (newly) grp[k] = cur;
            }
            ++cur;
            if (!(~(amask[0] & amask[1] & amask[2] & amask[3]))) break;
        }
    }

#pragma unroll
    for (int k = 0; k < 4; ++k) {
        const int j = b * NN + k * 64 + lane;
        out_groups_i[j] = grp[k];
        out_groups_f[j] = (float)grp[k];
    }
}

// ---------------------------------------------------------------------------
// Kernel 2: adjacency + intra, ONE SEQUENTIAL WRITE STREAM PER WAVE.
// Round-5 evidence: the 6-streams-per-wave layout ran at ~3.5 TB/s while the
// harness fill (1 stream/wave) hits 6.5+ TB/s on the same buffers — theory:
// concurrent-stream count exceeds HBM open-row capacity. Here:
//   block n in [0,1536): tensor = n>=768 (adj|intra); slab = n&767 encodes
//   ((b*3+s)*16+t)*2+half, i.e. consecutive blocks cover consecutive 128KB
//   output slabs. Wave rw writes rows [half*128+rw*32, +32) of one plane ->
//   a pure sequential 32KB stream per wave (1KB dwordx4 store per row).
// d/w recomputed per scale-plane (3x VALU redundancy, ~19us worst-case issue
// vs 31us memory floor — stays memory-bound).
// ---------------------------------------------------------------------------
#define PLANE_BLOCKS (NB * NS * NT * 2)   // 768 half-plane slabs per tensor

__global__ __launch_bounds__(256) void adj_kernel(
    const float* __restrict__ positions,
    const float* __restrict__ displacements,
    const int* __restrict__ groups,
    float* __restrict__ adj,
    float* __restrict__ intra)
{
    __shared__ float px[NN], py[NN], ux[NN], uy[NN];
    __shared__ int grp[NN];

    const int n       = blockIdx.x;
    const int isIntra = (n >= PLANE_BLOCKS) ? 1 : 0;
    const int slab    = isIntra ? (n - PLANE_BLOCKS) : n;
    const int half    = slab & 1;
    const int t       = (slab >> 1) & 15;
    const int bs      = slab >> 5;        // b*3 + s
    const int s       = bs % 3;
    const int b       = bs / 3;
    const int tid     = threadIdx.x;

    {
        const float2 p = ((const float2*)positions)[((size_t)b * NT + t) * NN + tid];
        const float2 u = ((const float2*)displacements)[((size_t)b * NT + t) * NN + tid];
        px[tid] = p.x;  py[tid] = p.y;
        ux[tid] = u.x;  uy[tid] = u.y;
        grp[tid] = groups[b * NN + tid];
    }
    __syncthreads();

    const int cl = tid & 63;   // column quad: cols 4*cl..4*cl+3
    const int rw = tid >> 6;   // wave id: owns rows half*128 + rw*32 .. +31

    const f32x4 pxj = ((const f32x4*)px)[cl];
    const f32x4 pyj = ((const f32x4*)py)[cl];
    const f32x4 uxj = ((const f32x4*)ux)[cl];
    const f32x4 uyj = ((const f32x4*)uy)[cl];
    const i32x4 gj  = ((const i32x4*)grp)[cl];

    const float S = (s == 0) ? 0.5f : ((s == 1) ? 1.0f : 2.0f);
    float* __restrict__ outp =
        (isIntra ? intra : adj) + ((size_t)bs * NT + t) * (size_t)(NN * NN);

    const int r0 = half * 128 + rw * 32;

    for (int q = 0; q < 32; ++q) {
        const int i = r0 + q;                       // wave-uniform row
        const float pix = px[i], piy = py[i];
        const float uix = ux[i], uiy = uy[i];
        const int   gi  = grp[i];

        f32x4 V;
#pragma unroll
        for (int cc = 0; cc < 4; ++cc) {
            const float dx = pix - pxj[cc];
            const float dy = piy - pyj[cc];
            const float sq = __fadd_rn(__fmul_rn(dx, dx), __fmul_rn(dy, dy));
            const float d  = __fsqrt_rn(sq);        // exact; sqrt(0)=0 matches ref

            const float ex = uix - uxj[cc];
            const float ey = uiy - uyj[cc];
            const float sqe = __fadd_rn(__fmul_rn(ex, ex), __fmul_rn(ey, ey));
            const float dn  = __builtin_amdgcn_sqrtf(sqe);
            const float w   = __builtin_amdgcn_rcpf(dn + 1e-6f);

            const float gmv = (gi == gj[cc]) ? 1.0f : 0.0f;
            const float fac = isIntra ? gmv : 1.0f;
            V[cc] = (d <= S) ? w * fac : 0.0f;
        }

        *(f32x4*)(outp + (size_t)i * NN + 4 * cl) = V;
    }
}

extern "C" void kernel_launch(void* const* d_in, const int* in_sizes, int n_in,
                              void* d_out, int out_size, void* d_ws, size_t ws_size,
                              hipStream_t stream) {
    const float* positions     = (const float*)d_in[0];
    const float* displacements = (const float*)d_in[1];
    float* out = (float*)d_out;

    const size_t ADJ_ELEMS = (size_t)NB * NS * NT * NN * NN;  // 25,165,824
    float* adj      = out;
    float* groups_f = out + ADJ_ELEMS;
    float* intra    = out + ADJ_ELEMS + (size_t)NB * NN;
    int*   groups_i = (int*)d_ws;

    groups_kernel<<<NB, 64, 0, stream>>>(positions, groups_f, groups_i);
    adj_kernel<<<2 * PLANE_BLOCKS, 256, 0, stream>>>(positions, displacements,
                                                     groups_i, adj, intra);
}

// Round 8
// 220.795 us; speedup vs baseline: 1.0006x; 1.0006x over previous
//
#include <hip/hip_runtime.h>

#define NB 8      // batches
#define NT 16     // timesteps
#define NN 256    // points
#define NS 3      // scales

typedef float f32x4 __attribute__((ext_vector_type(4)));
typedef int   i32x4 __attribute__((ext_vector_type(4)));

// ---------------------------------------------------------------------------
// Kernel 1: leader-clustering groups, ONE WAVE per batch, zero barriers.
// Bit-exact distance math (no fma contraction, correctly-rounded sqrt):
// group ids have zero error tolerance.
// ---------------------------------------------------------------------------
__global__ __launch_bounds__(64) void groups_kernel(
    const float* __restrict__ positions,
    float* __restrict__ out_groups_f,
    int* __restrict__ out_groups_i)
{
    const int b    = blockIdx.x;
    const int lane = threadIdx.x;

    const float2* __restrict__ P =
        ((const float2*)positions) + ((size_t)b * NT + (NT - 1)) * NN;

    float px[4], py[4];
#pragma unroll
    for (int k = 0; k < 4; ++k) {
        const float2 p = P[k * 64 + lane];
        px[k] = p.x; py[k] = p.y;
    }

    unsigned long long amask[4] = {0ull, 0ull, 0ull, 0ull};
    int grp[4] = {0, 0, 0, 0};
    int cur = 0;

#pragma unroll
    for (int ki = 0; ki < 4; ++ki) {
        for (int li = 0; li < 64; ++li) {
            if ((amask[ki] >> li) & 1ull) continue;
            const float pix = __shfl(px[ki], li);
            const float piy = __shfl(py[ki], li);
#pragma unroll
            for (int k = ki; k < 4; ++k) {
                const bool elig = (k > ki) || (lane >= li);
                const bool unas = (((amask[k] >> lane) & 1ull) == 0ull);
                const float dx = pix - px[k];
                const float dy = piy - py[k];
                const float sq = __fadd_rn(__fmul_rn(dx, dx), __fmul_rn(dy, dy));
                const float d  = (sq > 0.0f) ? __fsqrt_rn(sq) : 0.0f;
                const bool newly = elig && unas && (d <= 2.0f);
                const unsigned long long nb = __ballot(newly);
                amask[k] |= nb;
                if (newly) grp[k] = cur;
            }
            ++cur;
            if (!(~(amask[0] & amask[1] & amask[2] & amask[3]))) break;
        }
    }

#pragma unroll
    for (int k = 0; k < 4; ++k) {
        const int j = b * NN + k * 64 + lane;
        out_groups_i[j] = grp[k];
        out_groups_f[j] = (float)grp[k];
    }
}

// ---------------------------------------------------------------------------
// Kernel 2: adjacency + intra, sequential slab per wave + PHASE STAGGER.
// Evidence so far: 6x VALU swing -> no time change (not compute-bound);
// 6 streams vs 1 stream per wave -> no change (not stream-count-bound);
// plain stores beat nt by ~11us. Remaining theory: quasi-lockstep waves all
// write at the SAME intra-slab offset q*1KB at any instant -> address bits
// [10:14] nearly constant device-wide -> HBM channel-hash concentration ->
// ~half write BW vs the dense-sweeping rocclr fill (6.6 TB/s).
// Fix: rotate each wave's row order by a per-wave phase so all 32 q-residues
// are simultaneously in flight device-wide. Stores stay 1KB contiguous.
// ---------------------------------------------------------------------------
#define PLANE_BLOCKS (NB * NS * NT * 2)   // 768 half-plane slabs per tensor

__global__ __launch_bounds__(256) void adj_kernel(
    const float* __restrict__ positions,
    const float* __restrict__ displacements,
    const int* __restrict__ groups,
    float* __restrict__ adj,
    float* __restrict__ intra)
{
    __shared__ float px[NN], py[NN], ux[NN], uy[NN];
    __shared__ int grp[NN];

    const int n       = blockIdx.x;
    const int isIntra = (n >= PLANE_BLOCKS) ? 1 : 0;
    const int slab    = isIntra ? (n - PLANE_BLOCKS) : n;
    const int half    = slab & 1;
    const int t       = (slab >> 1) & 15;
    const int bs      = slab >> 5;        // b*3 + s
    const int s       = bs % 3;
    const int b       = bs / 3;
    const int tid     = threadIdx.x;

    {
        const float2 p = ((const float2*)positions)[((size_t)b * NT + t) * NN + tid];
        const float2 u = ((const float2*)displacements)[((size_t)b * NT + t) * NN + tid];
        px[tid] = p.x;  py[tid] = p.y;
        ux[tid] = u.x;  uy[tid] = u.y;
        grp[tid] = groups[b * NN + tid];
    }
    __syncthreads();

    const int cl = tid & 63;   // column quad: cols 4*cl..4*cl+3
    const int rw = tid >> 6;   // wave id: owns rows half*128 + rw*32 .. +31

    const f32x4 pxj = ((const f32x4*)px)[cl];
    const f32x4 pyj = ((const f32x4*)py)[cl];
    const f32x4 uxj = ((const f32x4*)ux)[cl];
    const f32x4 uyj = ((const f32x4*)uy)[cl];
    const i32x4 gj  = ((const i32x4*)grp)[cl];

    const float S = (s == 0) ? 0.5f : ((s == 1) ? 1.0f : 2.0f);
    float* __restrict__ outp =
        (isIntra ? intra : adj) + ((size_t)bs * NT + t) * (size_t)(NN * NN);

    const int r0    = half * 128 + rw * 32;
    const int phase = ((n * 4 + rw) * 13) & 31;   // per-wave row-order rotation

    for (int k = 0; k < 32; ++k) {
        const int q = (phase + k) & 31;
        const int i = r0 + q;                       // wave-uniform row
        const float pix = px[i], piy = py[i];
        const float uix = ux[i], uiy = uy[i];
        const int   gi  = grp[i];

        f32x4 V;
#pragma unroll
        for (int cc = 0; cc < 4; ++cc) {
            const float dx = pix - pxj[cc];
            const float dy = piy - pyj[cc];
            const float sq = __fadd_rn(__fmul_rn(dx, dx), __fmul_rn(dy, dy));
            const float d  = __fsqrt_rn(sq);        // exact; sqrt(0)=0 matches ref

            const float ex = uix - uxj[cc];
            const float ey = uiy - uyj[cc];
            const float sqe = __fadd_rn(__fmul_rn(ex, ex), __fmul_rn(ey, ey));
            const float dn  = __builtin_amdgcn_sqrtf(sqe);
            const float w   = __builtin_amdgcn_rcpf(dn + 1e-6f);

            const float gmv = (gi == gj[cc]) ? 1.0f : 0.0f;
            const float fac = isIntra ? gmv : 1.0f;
            V[cc] = (d <= S) ? w * fac : 0.0f;
        }

        *(f32x4*)(outp + (size_t)i * NN + 4 * cl) = V;
    }
}

extern "C" void kernel_launch(void* const* d_in, const int* in_sizes, int n_in,
                              void* d_out, int out_size, void* d_ws, size_t ws_size,
                              hipStream_t stream) {
    const float* positions     = (const float*)d_in[0];
    const float* displacements = (const float*)d_in[1];
    float* out = (float*)d_out;

    const size_t ADJ_ELEMS = (size_t)NB * NS * NT * NN * NN;  // 25,165,824
    float* adj      = out;
    float* groups_f = out + ADJ_ELEMS;
    float* intra    = out + ADJ_ELEMS + (size_t)NB * NN;
    int*   groups_i = (int*)d_ws;

    groups_kernel<<<NB, 64, 0, stream>>>(positions, groups_f, groups_i);
    adj_kernel<<<2 * PLANE_BLOCKS, 256, 0, stream>>>(positions, displacements,
                                                     groups_i, adj, intra);
}